// Round 1
// baseline (1748.001 us; speedup 1.0000x reference)
//
#include <hip/hip_runtime.h>
#include <hip/hip_bf16.h>
#include <stdint.h>

// SlotAttention on MI355X. Round 1: correct bf16-MFMA pipeline, fp32 master state.
// B=32 L=2048 D=1024 N=16 ITERS=4 H=2048.

typedef __bf16 bf16;
typedef __bf16 bf16x2 __attribute__((ext_vector_type(2)));
typedef __bf16 bf16x4 __attribute__((ext_vector_type(4)));
typedef __bf16 bf16x8 __attribute__((ext_vector_type(8)));
typedef float  f32x4  __attribute__((ext_vector_type(4)));

#define MFMA16(a,b,c) __builtin_amdgcn_mfma_f32_16x16x32_bf16((a),(b),(c),0,0,0)

__device__ __forceinline__ void gload16(const void* g, void* l) {
  __builtin_amdgcn_global_load_lds((__attribute__((address_space(1))) const void*)g,
                                   (__attribute__((address_space(3))) void*)l, 16, 0, 0);
}

// ---------------- generic bf16 GEMM:  C[M,N] = A[M,K] @ B[N,K]^T ----------------
// 4 waves as 2x2; BM = FM*32, BN = FN*32. 2-barrier m97-style loop.
template<int BM, int BN, int FM, int FN, int OUT_F32>
__global__ __launch_bounds__(256, 2)
void gemm_bt(const bf16* __restrict__ A, const bf16* __restrict__ B,
             void* __restrict__ C, int M, int N, int K)
{
  __shared__ __align__(16) bf16 As[BM * 64];
  __shared__ __align__(16) bf16 Bs[BN * 64];
  const int tid  = threadIdx.x;
  const int wave = tid >> 6, lane = tid & 63;
  const int wm = wave >> 1, wn = wave & 1;
  const int brow = blockIdx.y * BM, bcol = blockIdx.x * BN;
  const int r_a = lane >> 3;            // row within 8-row group
  const int c_a = (lane & 7) * 8;       // col (bf16 elems) within 64
  const int cl = lane & 15, rh = lane >> 4;

  f32x4 acc[FM][FN] = {};

  for (int k0 = 0; k0 < K; k0 += 64) {
    __syncthreads();
#pragma unroll
    for (int i = 0; i < BM / 32; ++i) {
      int row = i * 32 + wave * 8 + r_a;
      gload16(A + (size_t)(brow + row) * K + k0 + c_a, &As[(i * 32 + wave * 8) * 64]);
    }
#pragma unroll
    for (int i = 0; i < BN / 32; ++i) {
      int row = i * 32 + wave * 8 + r_a;
      gload16(B + (size_t)(bcol + row) * K + k0 + c_a, &Bs[(i * 32 + wave * 8) * 64]);
    }
    __syncthreads();
#pragma unroll
    for (int kk = 0; kk < 2; ++kk) {
      bf16x8 af[FM], bfv[FN];
#pragma unroll
      for (int m = 0; m < FM; ++m)
        af[m] = *(const bf16x8*)&As[(wm * (FM * 16) + m * 16 + cl) * 64 + kk * 32 + rh * 8];
#pragma unroll
      for (int n = 0; n < FN; ++n)
        bfv[n] = *(const bf16x8*)&Bs[(wn * (FN * 16) + n * 16 + cl) * 64 + kk * 32 + rh * 8];
#pragma unroll
      for (int m = 0; m < FM; ++m)
#pragma unroll
        for (int n = 0; n < FN; ++n)
          acc[m][n] = MFMA16(af[m], bfv[n], acc[m][n]);
    }
  }
  // epilogue: D row=(lane>>4)*4+reg, col=lane&15
#pragma unroll
  for (int m = 0; m < FM; ++m)
#pragma unroll
    for (int n = 0; n < FN; ++n) {
      int row0 = brow + wm * (FM * 16) + m * 16 + rh * 4;
      int col  = bcol + wn * (FN * 16) + n * 16 + cl;
#pragma unroll
      for (int r = 0; r < 4; ++r) {
        if (OUT_F32) ((float*)C)[(size_t)(row0 + r) * N + col] = acc[m][n][r];
        else         ((bf16*)C)[(size_t)(row0 + r) * N + col] = (bf16)acc[m][n][r];
      }
    }
}

// ---------------- dots = q k^T * scale, softmax over 16 slots, store attn_t [B][L][16] ----------------
__global__ __launch_bounds__(256, 2)
void dots_softmax(const bf16* __restrict__ q, const bf16* __restrict__ k,
                  bf16* __restrict__ attn_t, float* __restrict__ attn_sum)
{
  const int b = blockIdx.y, l0 = blockIdx.x * 256;
  const int tid = threadIdx.x, wave = tid >> 6, lane = tid & 63;
  const int cl = lane & 15, rh = lane >> 4;
  __shared__ __align__(16) bf16 qs[16 * 1024];   // 32KB, loaded once
  __shared__ __align__(16) bf16 ks[256 * 64];    // 32KB per K-step

  const bf16* qb = q + (size_t)b * 16 * 1024;
#pragma unroll
  for (int i = 0; i < 8; ++i)
    gload16(qb + i * 2048 + tid * 8, &qs[i * 2048 + wave * 512]);

  const bf16* kb = k + ((size_t)b * 2048 + l0) * 1024;
  f32x4 acc[4] = {};
  for (int kt = 0; kt < 16; ++kt) {
    __syncthreads();
#pragma unroll
    for (int i = 0; i < 8; ++i) {
      int row = i * 32 + wave * 8 + (lane >> 3);
      gload16(kb + (size_t)row * 1024 + kt * 64 + (lane & 7) * 8, &ks[(i * 32 + wave * 8) * 64]);
    }
    __syncthreads();
#pragma unroll
    for (int kk = 0; kk < 2; ++kk) {
      bf16x8 af = *(const bf16x8*)&qs[cl * 1024 + kt * 64 + kk * 32 + rh * 8];
#pragma unroll
      for (int n = 0; n < 4; ++n) {
        bf16x8 bfv = *(const bf16x8*)&ks[(wave * 64 + n * 16 + cl) * 64 + kk * 32 + rh * 8];
        acc[n] = MFMA16(af, bfv, acc[n]);
      }
    }
  }
  // softmax over slots: for a column l, 16 slot values live in lanes {cl,cl+16,cl+32,cl+48} x regs 0..3
  const float scale = 0.03125f;  // 1024^-0.5
  float rs[4] = {0.f, 0.f, 0.f, 0.f};
#pragma unroll
  for (int n = 0; n < 4; ++n) {
    float x[4];
#pragma unroll
    for (int r = 0; r < 4; ++r) x[r] = acc[n][r] * scale;
    float mx = fmaxf(fmaxf(x[0], x[1]), fmaxf(x[2], x[3]));
    mx = fmaxf(mx, __shfl_xor(mx, 16));
    mx = fmaxf(mx, __shfl_xor(mx, 32));
    float e[4], s = 0.f;
#pragma unroll
    for (int r = 0; r < 4; ++r) { e[r] = __expf(x[r] - mx); s += e[r]; }
    s += __shfl_xor(s, 16);
    s += __shfl_xor(s, 32);
    float inv = 1.f / s;
    bf16x4 pk;
#pragma unroll
    for (int r = 0; r < 4; ++r) { float av = e[r] * inv; rs[r] += av; pk[r] = (bf16)av; }
    int l = l0 + wave * 64 + n * 16 + cl;
    *(bf16x4*)(attn_t + ((size_t)b * 2048 + l) * 16 + rh * 4) = pk;
  }
  // denominator: sum over l (reduce across the 16 columns of this wave, then atomic)
#pragma unroll
  for (int off = 1; off < 16; off <<= 1) {
#pragma unroll
    for (int r = 0; r < 4; ++r) rs[r] += __shfl_xor(rs[r], off);
  }
  if (cl == 0) {
#pragma unroll
    for (int r = 0; r < 4; ++r) atomicAdd(&attn_sum[b * 16 + rh * 4 + r], rs[r]);
  }
}

// ---------------- updates partial: part[ls][b][n][d] = sum_{l in split} attn[n,l] * v[l,d] ----------------
__global__ __launch_bounds__(256, 4)
void updates_partial(const bf16* __restrict__ attn_t, const bf16* __restrict__ v,
                     float* __restrict__ part)
{
  const int tid = threadIdx.x;
  const int dh = blockIdx.x, ls = blockIdx.y, b = blockIdx.z;
  const int d0 = dh * 512 + tid * 2;
  float acc0[16] = {}, acc1[16] = {};
  const bf16* vb = v + ((size_t)b * 2048 + ls * 512) * 1024 + d0;
  const bf16* ab = attn_t + ((size_t)b * 2048 + ls * 512) * 16;
  for (int l = 0; l < 512; ++l) {
    bf16x2 vv = *(const bf16x2*)(vb + (size_t)l * 1024);
    float v0 = (float)vv[0], v1 = (float)vv[1];
    bf16x8 a0 = *(const bf16x8*)(ab + l * 16);
    bf16x8 a1 = *(const bf16x8*)(ab + l * 16 + 8);
#pragma unroll
    for (int n = 0; n < 8; ++n) { float an = (float)a0[n]; acc0[n] += an * v0; acc1[n] += an * v1; }
#pragma unroll
    for (int n = 0; n < 8; ++n) { float an = (float)a1[n]; acc0[8 + n] += an * v0; acc1[8 + n] += an * v1; }
  }
  float* pb = part + ((size_t)ls * 32 + b) * 16 * 1024 + d0;
#pragma unroll
  for (int n = 0; n < 16; ++n) { pb[(size_t)n * 1024] = acc0[n]; pb[(size_t)n * 1024 + 1] = acc1[n]; }
}

__global__ void updates_finalize(const float* __restrict__ part, const float* __restrict__ attn_sum,
                                 bf16* __restrict__ upd)
{
  int idx = blockIdx.x * 256 + threadIdx.x;     // over 512*1024
  int m = idx >> 10;
  float s = part[idx] + part[idx + 524288] + part[idx + 2 * 524288] + part[idx + 3 * 524288];
  upd[idx] = (bf16)(s / (attn_sum[m] + 1e-8f));
}

// ---------------- pointwise ----------------
__global__ void swiglu_pw(const float* __restrict__ h12, bf16* __restrict__ g)
{
  int idx = blockIdx.x * 256 + threadIdx.x;     // over 512*2048
  int m = idx >> 11, j = idx & 2047;
  float h1 = h12[(size_t)m * 4096 + j];
  float h2 = h12[(size_t)m * 4096 + 2048 + j];
  g[idx] = (bf16)(h1 / (1.f + __expf(-h1)) * h2);
}

__global__ void gru_pw(const float* __restrict__ gi, const float* __restrict__ gh,
                       const float* __restrict__ bih, const float* __restrict__ bhh,
                       float* __restrict__ slots, bf16* __restrict__ slots_bf,
                       float* __restrict__ outp)
{
  int idx = blockIdx.x * 256 + threadIdx.x;     // over 512*1024
  int m = idx >> 10, d = idx & 1023;
  size_t base = (size_t)m * 3072 + d;
  float r  = gi[base] + bih[d] + gh[base] + bhh[d];
  float z  = gi[base + 1024] + bih[1024 + d] + gh[base + 1024] + bhh[1024 + d];
  float nn = gi[base + 2048] + bih[2048 + d];
  float hn = gh[base + 2048] + bhh[2048 + d];
  r = 1.f / (1.f + expf(-r));
  z = 1.f / (1.f + expf(-z));
  nn = tanhf(nn + r * hn);
  float h = slots[idx];
  float o = (1.f - z) * nn + z * h;
  slots[idx] = o;
  slots_bf[idx] = (bf16)o;
  outp[idx] = o;
}

__global__ __launch_bounds__(256)
void rmsnorm_cast(const float* __restrict__ x, const float* __restrict__ g, bf16* __restrict__ y)
{
  const int row = blockIdx.x, tid = threadIdx.x;
  float4 xv = ((const float4*)(x + (size_t)row * 1024))[tid];
  float ss = xv.x * xv.x + xv.y * xv.y + xv.z * xv.z + xv.w * xv.w;
#pragma unroll
  for (int off = 32; off; off >>= 1) ss += __shfl_xor(ss, off);
  __shared__ float red[4];
  if ((tid & 63) == 0) red[tid >> 6] = ss;
  __syncthreads();
  float tot = red[0] + red[1] + red[2] + red[3];
  float rs = rsqrtf(tot * (1.f / 1024.f) + 1e-6f);
  float4 gv = ((const float4*)g)[tid];
  bf16x4 o;
  o[0] = (bf16)(xv.x * rs * gv.x); o[1] = (bf16)(xv.y * rs * gv.y);
  o[2] = (bf16)(xv.z * rs * gv.z); o[3] = (bf16)(xv.w * rs * gv.w);
  *(bf16x4*)(y + (size_t)row * 1024 + tid * 4) = o;
}

__global__ void init_slots(const float* __restrict__ noise, const float* __restrict__ mu,
                           const float* __restrict__ sigma, float* __restrict__ slots,
                           bf16* __restrict__ slots_bf)
{
  int idx = blockIdx.x * 256 + threadIdx.x;     // over 512*1024
  int d = idx & 1023;
  float v = mu[d] + sigma[d] * noise[idx];
  slots[idx] = v;
  slots_bf[idx] = (bf16)v;
}

__global__ void cast_bf16_x4(const float* __restrict__ x, bf16* __restrict__ y)
{
  int i = (blockIdx.x * 256 + threadIdx.x) * 4;
  float4 v = *(const float4*)(x + i);
  bf16x4 o; o[0] = (bf16)v.x; o[1] = (bf16)v.y; o[2] = (bf16)v.z; o[3] = (bf16)v.w;
  *(bf16x4*)(y + i) = o;
}

// ---------------- host ----------------
extern "C" void kernel_launch(void* const* d_in, const int* in_sizes, int n_in,
                              void* d_out, int out_size, void* d_ws, size_t ws_size,
                              hipStream_t stream)
{
  const float* enc    = (const float*)d_in[0];
  const float* noise  = (const float*)d_in[1];
  const float* mu     = (const float*)d_in[2];
  const float* sigma  = (const float*)d_in[3];
  const float* g_in   = (const float*)d_in[4];
  const float* g_sl   = (const float*)d_in[5];
  const float* Wq     = (const float*)d_in[6];
  const float* Wk     = (const float*)d_in[7];
  const float* Wv     = (const float*)d_in[8];
  const float* w1     = (const float*)d_in[9];
  const float* w2     = (const float*)d_in[10];
  const float* w3     = (const float*)d_in[11];
  const float* Wih    = (const float*)d_in[12];
  const float* Whh    = (const float*)d_in[13];
  const float* bih    = (const float*)d_in[14];
  const float* bhh    = (const float*)d_in[15];

  char* p = (char*)d_ws;
  auto alloc = [&](size_t bytes) { char* r = p; p += (bytes + 255) & ~(size_t)255; return (void*)r; };

  bf16* inputs  = (bf16*)alloc((size_t)32 * 2048 * 1024 * 2);  // 128MB
  bf16* kbuf    = (bf16*)alloc((size_t)32 * 2048 * 1024 * 2);  // 128MB
  bf16* vbuf    = (bf16*)alloc((size_t)32 * 2048 * 1024 * 2);  // 128MB
  bf16* wq_b    = (bf16*)alloc(1024 * 1024 * 2);
  bf16* wk_b    = (bf16*)alloc(1024 * 1024 * 2);
  bf16* wv_b    = (bf16*)alloc(1024 * 1024 * 2);
  bf16* w12_b   = (bf16*)alloc((size_t)4096 * 1024 * 2);
  bf16* w3_b    = (bf16*)alloc((size_t)1024 * 2048 * 2);
  bf16* wih_b   = (bf16*)alloc((size_t)3072 * 1024 * 2);
  bf16* whh_b   = (bf16*)alloc((size_t)3072 * 1024 * 2);
  float* slots  = (float*)alloc(512 * 1024 * 4);
  bf16* slots_bf= (bf16*)alloc(512 * 1024 * 2);
  bf16* s_bf    = (bf16*)alloc(512 * 1024 * 2);
  bf16* q_bf    = (bf16*)alloc(512 * 1024 * 2);
  bf16* attn_t  = (bf16*)alloc((size_t)32 * 2048 * 16 * 2);
  float* attn_sum = (float*)alloc(32 * 16 * 4);
  float* part   = (float*)alloc((size_t)4 * 512 * 1024 * 4);   // 8MB
  bf16* upd_bf  = (bf16*)alloc(512 * 1024 * 2);
  float* h12    = (float*)alloc((size_t)512 * 4096 * 4);       // 8MB
  bf16* g_bf    = (bf16*)alloc((size_t)512 * 2048 * 2);
  bf16* swout   = (bf16*)alloc(512 * 1024 * 2);
  float* gif    = (float*)alloc((size_t)512 * 3072 * 4);
  float* ghf    = (float*)alloc((size_t)512 * 3072 * 4);

  // weight casts
  cast_bf16_x4<<<1024, 256, 0, stream>>>(Wq, wq_b);
  cast_bf16_x4<<<1024, 256, 0, stream>>>(Wk, wk_b);
  cast_bf16_x4<<<1024, 256, 0, stream>>>(Wv, wv_b);
  cast_bf16_x4<<<2048, 256, 0, stream>>>(w1, w12_b);
  cast_bf16_x4<<<2048, 256, 0, stream>>>(w2, w12_b + (size_t)2048 * 1024);
  cast_bf16_x4<<<2048, 256, 0, stream>>>(w3, w3_b);
  cast_bf16_x4<<<3072, 256, 0, stream>>>(Wih, wih_b);
  cast_bf16_x4<<<3072, 256, 0, stream>>>(Whh, whh_b);

  // stage 1
  rmsnorm_cast<<<65536, 256, 0, stream>>>(enc, g_in, inputs);
  init_slots<<<2048, 256, 0, stream>>>(noise, mu, sigma, slots, slots_bf);
  gemm_bt<128, 128, 4, 4, 0><<<dim3(8, 512), 256, 0, stream>>>(inputs, wk_b, kbuf, 65536, 1024, 1024);
  gemm_bt<128, 128, 4, 4, 0><<<dim3(8, 512), 256, 0, stream>>>(inputs, wv_b, vbuf, 65536, 1024, 1024);

  for (int it = 0; it < 4; ++it) {
    rmsnorm_cast<<<512, 256, 0, stream>>>(slots, g_sl, s_bf);
    gemm_bt<64, 128, 2, 4, 0><<<dim3(8, 8), 256, 0, stream>>>(s_bf, wq_b, q_bf, 512, 1024, 1024);
    hipMemsetAsync(attn_sum, 0, 32 * 16 * 4, stream);
    dots_softmax<<<dim3(8, 32), 256, 0, stream>>>(q_bf, kbuf, attn_t, attn_sum);
    updates_partial<<<dim3(2, 4, 32), 256, 0, stream>>>(attn_t, vbuf, part);
    updates_finalize<<<2048, 256, 0, stream>>>(part, attn_sum, upd_bf);
    gemm_bt<64, 128, 2, 4, 1><<<dim3(32, 8), 256, 0, stream>>>(upd_bf, w12_b, h12, 512, 4096, 1024);
    swiglu_pw<<<4096, 256, 0, stream>>>(h12, g_bf);
    gemm_bt<64, 128, 2, 4, 0><<<dim3(8, 8), 256, 0, stream>>>(g_bf, w3_b, swout, 512, 1024, 2048);
    gemm_bt<64, 128, 2, 4, 1><<<dim3(24, 8), 256, 0, stream>>>(swout, wih_b, gif, 512, 3072, 1024);
    gemm_bt<64, 128, 2, 4, 1><<<dim3(24, 8), 256, 0, stream>>>(slots_bf, whh_b, ghf, 512, 3072, 1024);
    float* outp = (it == 3) ? (float*)d_out : slots;
    gru_pw<<<2048, 256, 0, stream>>>(gif, ghf, bih, bhh, slots, slots_bf, outp);
  }
}

// Round 2
// 1176.905 us; speedup vs baseline: 1.4853x; 1.4853x over previous
//
#include <hip/hip_runtime.h>
#include <hip/hip_bf16.h>
#include <stdint.h>

// SlotAttention MI355X. Round 2: fused KV GEMM + XCD swizzle, SwiGLU-fused GEMM,
// z-batched GRU GEMMs, f32 attn, wider grids for loop kernels.
// B=32 L=2048 D=1024 N=16 ITERS=4 H=2048.

typedef __bf16 bf16;
typedef __bf16 bf16x2 __attribute__((ext_vector_type(2)));
typedef __bf16 bf16x4 __attribute__((ext_vector_type(4)));
typedef __bf16 bf16x8 __attribute__((ext_vector_type(8)));
typedef float  f32x4  __attribute__((ext_vector_type(4)));

#define MFMA16(a,b,c) __builtin_amdgcn_mfma_f32_16x16x32_bf16((a),(b),(c),0,0,0)

__device__ __forceinline__ void gload16(const void* g, void* l) {
  __builtin_amdgcn_global_load_lds((__attribute__((address_space(1))) const void*)g,
                                   (__attribute__((address_space(3))) void*)l, 16, 0, 0);
}

// ---------------- fused K/V GEMM: C[M,2048] = A[M,1024] @ Wkv[2048,1024]^T ----------------
// 128x128 tile, 4 waves 2x2, XCD-chunked block swizzle; cols<1024 -> kbuf, else vbuf.
__global__ __launch_bounds__(256, 2)
void gemm_kv(const bf16* __restrict__ A, const bf16* __restrict__ B,
             bf16* __restrict__ kout, bf16* __restrict__ vout)
{
  __shared__ __align__(16) bf16 As[128 * 64];
  __shared__ __align__(16) bf16 Bs[128 * 64];
  const int tid  = threadIdx.x;
  const int wave = tid >> 6, lane = tid & 63;
  const int wm = wave >> 1, wn = wave & 1;
  // grid (16, 512): XCD-chunked bijective swizzle (nwg=8192, 1024/XCD)
  const int id  = blockIdx.y * 16 + blockIdx.x;
  const int vid = (id & 7) * 1024 + (id >> 3);
  const int brow = (vid >> 4) * 128, bcol = (vid & 15) * 128;
  const int r8 = lane >> 3, c8 = (lane & 7) * 8;
  const int cl = lane & 15, rh = lane >> 4;
  const int K = 1024;

  f32x4 acc[4][4] = {};

  for (int k0 = 0; k0 < K; k0 += 64) {
    __syncthreads();
#pragma unroll
    for (int i = 0; i < 4; ++i)
      gload16(A + (size_t)(brow + i * 32 + wave * 8 + r8) * K + k0 + c8, &As[(i * 32 + wave * 8) * 64]);
#pragma unroll
    for (int i = 0; i < 4; ++i)
      gload16(B + (size_t)(bcol + i * 32 + wave * 8 + r8) * K + k0 + c8, &Bs[(i * 32 + wave * 8) * 64]);
    __syncthreads();
#pragma unroll
    for (int kk = 0; kk < 2; ++kk) {
      bf16x8 af[4], bfv[4];
#pragma unroll
      for (int m = 0; m < 4; ++m)
        af[m] = *(const bf16x8*)&As[(wm * 64 + m * 16 + cl) * 64 + kk * 32 + rh * 8];
#pragma unroll
      for (int n = 0; n < 4; ++n)
        bfv[n] = *(const bf16x8*)&Bs[(wn * 64 + n * 16 + cl) * 64 + kk * 32 + rh * 8];
#pragma unroll
      for (int m = 0; m < 4; ++m)
#pragma unroll
        for (int n = 0; n < 4; ++n)
          acc[m][n] = MFMA16(af[m], bfv[n], acc[m][n]);
    }
  }
  bf16* __restrict__ C = (bcol < 1024) ? kout : vout;
  const int cbase = (bcol < 1024) ? bcol : bcol - 1024;
#pragma unroll
  for (int m = 0; m < 4; ++m)
#pragma unroll
    for (int n = 0; n < 4; ++n) {
      int row0 = brow + wm * 64 + m * 16 + rh * 4;
      int col  = cbase + wn * 64 + n * 16 + cl;
#pragma unroll
      for (int r = 0; r < 4; ++r)
        C[(size_t)(row0 + r) * 1024 + col] = (bf16)acc[m][n][r];
    }
}

// ---------------- generic 64x64 GEMM (z selects problem): C[M,N] = A[M,K] @ B[N,K]^T ----------------
template<int OUT_F32>
__global__ __launch_bounds__(256, 4)
void gemm_bt64(const bf16* __restrict__ A0, const bf16* __restrict__ B0, void* __restrict__ C0,
               const bf16* __restrict__ A1, const bf16* __restrict__ B1, void* __restrict__ C1,
               int N, int K)
{
  const bf16* A = blockIdx.z ? A1 : A0;
  const bf16* B = blockIdx.z ? B1 : B0;
  void* C = blockIdx.z ? C1 : C0;
  __shared__ __align__(16) bf16 As[64 * 64];
  __shared__ __align__(16) bf16 Bs[64 * 64];
  const int tid = threadIdx.x, wave = tid >> 6, lane = tid & 63;
  const int wm = wave >> 1, wn = wave & 1;
  const int brow = blockIdx.y * 64, bcol = blockIdx.x * 64;
  const int r8 = lane >> 3, c8 = (lane & 7) * 8;
  const int cl = lane & 15, rh = lane >> 4;
  f32x4 acc[2][2] = {};

  for (int k0 = 0; k0 < K; k0 += 64) {
    __syncthreads();
    gload16(A + (size_t)(brow + wave * 16 + r8) * K + k0 + c8,     &As[(wave * 16) * 64]);
    gload16(A + (size_t)(brow + wave * 16 + 8 + r8) * K + k0 + c8, &As[(wave * 16 + 8) * 64]);
    gload16(B + (size_t)(bcol + wave * 16 + r8) * K + k0 + c8,     &Bs[(wave * 16) * 64]);
    gload16(B + (size_t)(bcol + wave * 16 + 8 + r8) * K + k0 + c8, &Bs[(wave * 16 + 8) * 64]);
    __syncthreads();
#pragma unroll
    for (int kk = 0; kk < 2; ++kk) {
      bf16x8 af[2], bfv[2];
#pragma unroll
      for (int m = 0; m < 2; ++m)
        af[m] = *(const bf16x8*)&As[(wm * 32 + m * 16 + cl) * 64 + kk * 32 + rh * 8];
#pragma unroll
      for (int n = 0; n < 2; ++n)
        bfv[n] = *(const bf16x8*)&Bs[(wn * 32 + n * 16 + cl) * 64 + kk * 32 + rh * 8];
#pragma unroll
      for (int m = 0; m < 2; ++m)
#pragma unroll
        for (int n = 0; n < 2; ++n)
          acc[m][n] = MFMA16(af[m], bfv[n], acc[m][n]);
    }
  }
#pragma unroll
  for (int m = 0; m < 2; ++m)
#pragma unroll
    for (int n = 0; n < 2; ++n) {
      int row0 = brow + wm * 32 + m * 16 + rh * 4;
      int col  = bcol + wn * 32 + n * 16 + cl;
#pragma unroll
      for (int r = 0; r < 4; ++r) {
        if (OUT_F32) ((float*)C)[(size_t)(row0 + r) * N + col] = acc[m][n][r];
        else         ((bf16*)C)[(size_t)(row0 + r) * N + col] = (bf16)acc[m][n][r];
      }
    }
}

// ---------------- SwiGLU-fused GEMM: G[512,2048] = silu(A@w1^T) * (A@w2^T), B12=[w1;w2] ----------------
__global__ __launch_bounds__(256, 4)
void gemm_swiglu(const bf16* __restrict__ A, const bf16* __restrict__ B12, bf16* __restrict__ G)
{
  __shared__ __align__(16) bf16 As[64 * 64];
  __shared__ __align__(16) bf16 B1s[64 * 64];
  __shared__ __align__(16) bf16 B2s[64 * 64];
  const int tid = threadIdx.x, wave = tid >> 6, lane = tid & 63;
  const int wm = wave >> 1, wn = wave & 1;
  const int brow = blockIdx.y * 64, bcol = blockIdx.x * 64;
  const int r8 = lane >> 3, c8 = (lane & 7) * 8;
  const int cl = lane & 15, rh = lane >> 4;
  f32x4 acc1[2][2] = {}, acc2[2][2] = {};

  for (int k0 = 0; k0 < 1024; k0 += 64) {
    __syncthreads();
    gload16(A   + (size_t)(brow + wave * 16 + r8) * 1024 + k0 + c8,            &As[(wave * 16) * 64]);
    gload16(A   + (size_t)(brow + wave * 16 + 8 + r8) * 1024 + k0 + c8,        &As[(wave * 16 + 8) * 64]);
    gload16(B12 + (size_t)(bcol + wave * 16 + r8) * 1024 + k0 + c8,            &B1s[(wave * 16) * 64]);
    gload16(B12 + (size_t)(bcol + wave * 16 + 8 + r8) * 1024 + k0 + c8,        &B1s[(wave * 16 + 8) * 64]);
    gload16(B12 + (size_t)(2048 + bcol + wave * 16 + r8) * 1024 + k0 + c8,     &B2s[(wave * 16) * 64]);
    gload16(B12 + (size_t)(2048 + bcol + wave * 16 + 8 + r8) * 1024 + k0 + c8, &B2s[(wave * 16 + 8) * 64]);
    __syncthreads();
#pragma unroll
    for (int kk = 0; kk < 2; ++kk) {
      bf16x8 af[2], b1v[2], b2v[2];
#pragma unroll
      for (int m = 0; m < 2; ++m)
        af[m] = *(const bf16x8*)&As[(wm * 32 + m * 16 + cl) * 64 + kk * 32 + rh * 8];
#pragma unroll
      for (int n = 0; n < 2; ++n) {
        b1v[n] = *(const bf16x8*)&B1s[(wn * 32 + n * 16 + cl) * 64 + kk * 32 + rh * 8];
        b2v[n] = *(const bf16x8*)&B2s[(wn * 32 + n * 16 + cl) * 64 + kk * 32 + rh * 8];
      }
#pragma unroll
      for (int m = 0; m < 2; ++m)
#pragma unroll
        for (int n = 0; n < 2; ++n) {
          acc1[m][n] = MFMA16(af[m], b1v[n], acc1[m][n]);
          acc2[m][n] = MFMA16(af[m], b2v[n], acc2[m][n]);
        }
    }
  }
#pragma unroll
  for (int m = 0; m < 2; ++m)
#pragma unroll
    for (int n = 0; n < 2; ++n) {
      int row0 = brow + wm * 32 + m * 16 + rh * 4;
      int col  = bcol + wn * 32 + n * 16 + cl;
#pragma unroll
      for (int r = 0; r < 4; ++r) {
        float h1 = acc1[m][n][r], h2 = acc2[m][n][r];
        G[(size_t)(row0 + r) * 2048 + col] = (bf16)(h1 / (1.f + __expf(-h1)) * h2);
      }
    }
}

// ---------------- dots + softmax over 16 slots, attn (f32) [B][L][16] ----------------
__global__ __launch_bounds__(256, 3)
void dots_softmax(const bf16* __restrict__ q, const bf16* __restrict__ k,
                  float* __restrict__ attn_t, float* __restrict__ attn_sum)
{
  const int b = blockIdx.y, l0 = blockIdx.x * 128;
  const int tid = threadIdx.x, wave = tid >> 6, lane = tid & 63;
  const int cl = lane & 15, rh = lane >> 4;
  __shared__ __align__(16) bf16 qs[16 * 1024];   // 32KB
  __shared__ __align__(16) bf16 ks[128 * 64];    // 16KB

  const bf16* qb = q + (size_t)b * 16 * 1024;
#pragma unroll
  for (int i = 0; i < 8; ++i)
    gload16(qb + i * 2048 + tid * 8, &qs[i * 2048 + wave * 512]);

  const bf16* kb = k + ((size_t)b * 2048 + l0) * 1024;
  f32x4 acc[2] = {};
  for (int kt = 0; kt < 16; ++kt) {
    __syncthreads();
#pragma unroll
    for (int i = 0; i < 4; ++i) {
      int row = i * 32 + wave * 8 + (lane >> 3);
      gload16(kb + (size_t)row * 1024 + kt * 64 + (lane & 7) * 8, &ks[(i * 32 + wave * 8) * 64]);
    }
    __syncthreads();
#pragma unroll
    for (int kk = 0; kk < 2; ++kk) {
      bf16x8 af = *(const bf16x8*)&qs[cl * 1024 + kt * 64 + kk * 32 + rh * 8];
#pragma unroll
      for (int n = 0; n < 2; ++n) {
        bf16x8 bfv = *(const bf16x8*)&ks[(wave * 32 + n * 16 + cl) * 64 + kk * 32 + rh * 8];
        acc[n] = MFMA16(af, bfv, acc[n]);
      }
    }
  }
  const float scale = 0.03125f;  // 1024^-0.5
  float rs[4] = {0.f, 0.f, 0.f, 0.f};
#pragma unroll
  for (int n = 0; n < 2; ++n) {
    float x[4];
#pragma unroll
    for (int r = 0; r < 4; ++r) x[r] = acc[n][r] * scale;
    float mx = fmaxf(fmaxf(x[0], x[1]), fmaxf(x[2], x[3]));
    mx = fmaxf(mx, __shfl_xor(mx, 16));
    mx = fmaxf(mx, __shfl_xor(mx, 32));
    float e[4], s = 0.f;
#pragma unroll
    for (int r = 0; r < 4; ++r) { e[r] = __expf(x[r] - mx); s += e[r]; }
    s += __shfl_xor(s, 16);
    s += __shfl_xor(s, 32);
    float inv = 1.f / s;
    f32x4 pk;
#pragma unroll
    for (int r = 0; r < 4; ++r) { float av = e[r] * inv; rs[r] += av; pk[r] = av; }
    int l = l0 + wave * 32 + n * 16 + cl;
    *(f32x4*)(attn_t + ((size_t)b * 2048 + l) * 16 + rh * 4) = pk;
  }
#pragma unroll
  for (int off = 1; off < 16; off <<= 1) {
#pragma unroll
    for (int r = 0; r < 4; ++r) rs[r] += __shfl_xor(rs[r], off);
  }
  if (cl == 0) {
#pragma unroll
    for (int r = 0; r < 4; ++r) atomicAdd(&attn_sum[b * 16 + rh * 4 + r], rs[r]);
  }
}

// ---------------- updates partial over l-splits ----------------
__global__ __launch_bounds__(256, 4)
void updates_partial(const float* __restrict__ attn_t, const bf16* __restrict__ v,
                     float* __restrict__ part)
{
  const int tid = threadIdx.x;
  const int dh = blockIdx.x, ls = blockIdx.y, b = blockIdx.z;
  const int d0 = dh * 512 + tid * 2;
  float acc0[16] = {}, acc1[16] = {};
  const bf16* vb = v + ((size_t)b * 2048 + ls * 256) * 1024 + d0;
  const float* ab = attn_t + ((size_t)b * 2048 + ls * 256) * 16;
  for (int l = 0; l < 256; ++l) {
    bf16x2 vv = *(const bf16x2*)(vb + (size_t)l * 1024);
    float v0 = (float)vv[0], v1 = (float)vv[1];
    f32x4 a0 = *(const f32x4*)(ab + l * 16);
    f32x4 a1 = *(const f32x4*)(ab + l * 16 + 4);
    f32x4 a2 = *(const f32x4*)(ab + l * 16 + 8);
    f32x4 a3 = *(const f32x4*)(ab + l * 16 + 12);
#pragma unroll
    for (int j = 0; j < 4; ++j) { acc0[j]      += a0[j] * v0; acc1[j]      += a0[j] * v1; }
#pragma unroll
    for (int j = 0; j < 4; ++j) { acc0[4 + j]  += a1[j] * v0; acc1[4 + j]  += a1[j] * v1; }
#pragma unroll
    for (int j = 0; j < 4; ++j) { acc0[8 + j]  += a2[j] * v0; acc1[8 + j]  += a2[j] * v1; }
#pragma unroll
    for (int j = 0; j < 4; ++j) { acc0[12 + j] += a3[j] * v0; acc1[12 + j] += a3[j] * v1; }
  }
  float* pb = part + ((size_t)ls * 32 + b) * 16384 + d0;
#pragma unroll
  for (int n = 0; n < 16; ++n) { pb[(size_t)n * 1024] = acc0[n]; pb[(size_t)n * 1024 + 1] = acc1[n]; }
}

__global__ void updates_finalize(const float* __restrict__ part, const float* __restrict__ attn_sum,
                                 bf16* __restrict__ upd)
{
  int idx = blockIdx.x * 256 + threadIdx.x;     // over 512*1024
  int m = idx >> 10;
  float s = 0.f;
#pragma unroll
  for (int ls = 0; ls < 8; ++ls) s += part[idx + (size_t)ls * 524288];
  upd[idx] = (bf16)(s / (attn_sum[m] + 1e-8f));
}

// ---------------- pointwise ----------------
__global__ void gru_pw(const float* __restrict__ gi, const float* __restrict__ gh,
                       const float* __restrict__ bih, const float* __restrict__ bhh,
                       float* __restrict__ slots, bf16* __restrict__ slots_bf,
                       float* __restrict__ outp)
{
  int idx = blockIdx.x * 256 + threadIdx.x;     // over 512*1024
  int m = idx >> 10, d = idx & 1023;
  size_t base = (size_t)m * 3072 + d;
  float r  = gi[base] + bih[d] + gh[base] + bhh[d];
  float z  = gi[base + 1024] + bih[1024 + d] + gh[base + 1024] + bhh[1024 + d];
  float nn = gi[base + 2048] + bih[2048 + d];
  float hn = gh[base + 2048] + bhh[2048 + d];
  r = 1.f / (1.f + expf(-r));
  z = 1.f / (1.f + expf(-z));
  nn = tanhf(nn + r * hn);
  float h = slots[idx];
  float o = (1.f - z) * nn + z * h;
  slots[idx] = o;
  slots_bf[idx] = (bf16)o;
  outp[idx] = o;
}

__global__ __launch_bounds__(256)
void rmsnorm_cast(const float* __restrict__ x, const float* __restrict__ g, bf16* __restrict__ y)
{
  const int row = blockIdx.x, tid = threadIdx.x;
  float4 xv = ((const float4*)(x + (size_t)row * 1024))[tid];
  float ss = xv.x * xv.x + xv.y * xv.y + xv.z * xv.z + xv.w * xv.w;
#pragma unroll
  for (int off = 32; off; off >>= 1) ss += __shfl_xor(ss, off);
  __shared__ float red[4];
  if ((tid & 63) == 0) red[tid >> 6] = ss;
  __syncthreads();
  float tot = red[0] + red[1] + red[2] + red[3];
  float rs = rsqrtf(tot * (1.f / 1024.f) + 1e-6f);
  float4 gv = ((const float4*)g)[tid];
  bf16x4 o;
  o[0] = (bf16)(xv.x * rs * gv.x); o[1] = (bf16)(xv.y * rs * gv.y);
  o[2] = (bf16)(xv.z * rs * gv.z); o[3] = (bf16)(xv.w * rs * gv.w);
  *(bf16x4*)(y + (size_t)row * 1024 + tid * 4) = o;
}

__global__ void init_slots(const float* __restrict__ noise, const float* __restrict__ mu,
                           const float* __restrict__ sigma, float* __restrict__ slots,
                           bf16* __restrict__ slots_bf)
{
  int idx = blockIdx.x * 256 + threadIdx.x;     // over 512*1024
  int d = idx & 1023;
  float v = mu[d] + sigma[d] * noise[idx];
  slots[idx] = v;
  slots_bf[idx] = (bf16)v;
}

__global__ void cast_bf16_x4(const float* __restrict__ x, bf16* __restrict__ y)
{
  int i = (blockIdx.x * 256 + threadIdx.x) * 4;
  float4 v = *(const float4*)(x + i);
  bf16x4 o; o[0] = (bf16)v.x; o[1] = (bf16)v.y; o[2] = (bf16)v.z; o[3] = (bf16)v.w;
  *(bf16x4*)(y + i) = o;
}

// ---------------- host ----------------
extern "C" void kernel_launch(void* const* d_in, const int* in_sizes, int n_in,
                              void* d_out, int out_size, void* d_ws, size_t ws_size,
                              hipStream_t stream)
{
  const float* enc    = (const float*)d_in[0];
  const float* noise  = (const float*)d_in[1];
  const float* mu     = (const float*)d_in[2];
  const float* sigma  = (const float*)d_in[3];
  const float* g_in   = (const float*)d_in[4];
  const float* g_sl   = (const float*)d_in[5];
  const float* Wq     = (const float*)d_in[6];
  const float* Wk     = (const float*)d_in[7];
  const float* Wv     = (const float*)d_in[8];
  const float* w1     = (const float*)d_in[9];
  const float* w2     = (const float*)d_in[10];
  const float* w3     = (const float*)d_in[11];
  const float* Wih    = (const float*)d_in[12];
  const float* Whh    = (const float*)d_in[13];
  const float* bih    = (const float*)d_in[14];
  const float* bhh    = (const float*)d_in[15];

  char* p = (char*)d_ws;
  auto alloc = [&](size_t bytes) { char* r = p; p += (bytes + 255) & ~(size_t)255; return (void*)r; };

  bf16* inputs  = (bf16*)alloc((size_t)32 * 2048 * 1024 * 2);  // 128MB
  bf16* kbuf    = (bf16*)alloc((size_t)32 * 2048 * 1024 * 2);  // 128MB
  bf16* vbuf    = (bf16*)alloc((size_t)32 * 2048 * 1024 * 2);  // 128MB
  bf16* wq_b    = (bf16*)alloc(1024 * 1024 * 2);
  bf16* wkv_b   = (bf16*)alloc((size_t)2048 * 1024 * 2);       // [Wk; Wv]
  bf16* w12_b   = (bf16*)alloc((size_t)4096 * 1024 * 2);       // [w1; w2]
  bf16* w3_b    = (bf16*)alloc((size_t)1024 * 2048 * 2);
  bf16* wih_b   = (bf16*)alloc((size_t)3072 * 1024 * 2);
  bf16* whh_b   = (bf16*)alloc((size_t)3072 * 1024 * 2);
  float* slots  = (float*)alloc(512 * 1024 * 4);
  bf16* slots_bf= (bf16*)alloc(512 * 1024 * 2);
  bf16* s_bf    = (bf16*)alloc(512 * 1024 * 2);
  bf16* q_bf    = (bf16*)alloc(512 * 1024 * 2);
  float* attn_t = (float*)alloc((size_t)32 * 2048 * 16 * 4);   // 4MB f32
  float* attn_sum = (float*)alloc(32 * 16 * 4);
  float* part   = (float*)alloc((size_t)8 * 512 * 1024 * 4);   // 16MB
  bf16* upd_bf  = (bf16*)alloc(512 * 1024 * 2);
  bf16* g_bf    = (bf16*)alloc((size_t)512 * 2048 * 2);
  bf16* swout   = (bf16*)alloc(512 * 1024 * 2);
  float* gif    = (float*)alloc((size_t)512 * 3072 * 4);
  float* ghf    = (float*)alloc((size_t)512 * 3072 * 4);

  // weight casts
  cast_bf16_x4<<<1024, 256, 0, stream>>>(Wq, wq_b);
  cast_bf16_x4<<<1024, 256, 0, stream>>>(Wk, wkv_b);
  cast_bf16_x4<<<1024, 256, 0, stream>>>(Wv, wkv_b + (size_t)1024 * 1024);
  cast_bf16_x4<<<2048, 256, 0, stream>>>(w1, w12_b);
  cast_bf16_x4<<<2048, 256, 0, stream>>>(w2, w12_b + (size_t)2048 * 1024);
  cast_bf16_x4<<<2048, 256, 0, stream>>>(w3, w3_b);
  cast_bf16_x4<<<3072, 256, 0, stream>>>(Wih, wih_b);
  cast_bf16_x4<<<3072, 256, 0, stream>>>(Whh, whh_b);

  // stage 1
  rmsnorm_cast<<<65536, 256, 0, stream>>>(enc, g_in, inputs);
  init_slots<<<2048, 256, 0, stream>>>(noise, mu, sigma, slots, slots_bf);
  gemm_kv<<<dim3(16, 512), 256, 0, stream>>>(inputs, wkv_b, kbuf, vbuf);

  for (int it = 0; it < 4; ++it) {
    rmsnorm_cast<<<512, 256, 0, stream>>>(slots, g_sl, s_bf);
    gemm_bt64<0><<<dim3(16, 8, 1), 256, 0, stream>>>(s_bf, wq_b, q_bf, s_bf, wq_b, q_bf, 1024, 1024);
    hipMemsetAsync(attn_sum, 0, 32 * 16 * 4, stream);
    dots_softmax<<<dim3(16, 32), 256, 0, stream>>>(q_bf, kbuf, attn_t, attn_sum);
    updates_partial<<<dim3(2, 8, 32), 256, 0, stream>>>(attn_t, vbuf, part);
    updates_finalize<<<2048, 256, 0, stream>>>(part, attn_sum, upd_bf);
    gemm_swiglu<<<dim3(32, 8), 256, 0, stream>>>(upd_bf, w12_b, g_bf);
    gemm_bt64<0><<<dim3(16, 8, 1), 256, 0, stream>>>(g_bf, w3_b, swout, g_bf, w3_b, swout, 1024, 2048);
    gemm_bt64<1><<<dim3(48, 8, 2), 256, 0, stream>>>(swout, wih_b, gif, slots_bf, whh_b, ghf, 3072, 1024);
    float* outp = (it == 3) ? (float*)d_out : slots;
    gru_pw<<<2048, 256, 0, stream>>>(gif, ghf, bih, bhh, slots, slots_bf, outp);
  }
}

// Round 3
// 1087.551 us; speedup vs baseline: 1.6073x; 1.0822x over previous
//
#include <hip/hip_runtime.h>
#include <hip/hip_bf16.h>
#include <stdint.h>

// SlotAttention MI355X. Round 3: Wq folded into K-projection (M = Wq^T Wk),
// fused dots+softmax+PV kernel, rmsnorm folded into gru_pw/init.
// B=32 L=2048 D=1024 N=16 ITERS=4 H=2048.

typedef __bf16 bf16;
typedef __bf16 bf16x2 __attribute__((ext_vector_type(2)));
typedef __bf16 bf16x4 __attribute__((ext_vector_type(4)));
typedef __bf16 bf16x8 __attribute__((ext_vector_type(8)));
typedef float  f32x4  __attribute__((ext_vector_type(4)));

#define MFMA16(a,b,c) __builtin_amdgcn_mfma_f32_16x16x32_bf16((a),(b),(c),0,0,0)

__device__ __forceinline__ void gload16(const void* g, void* l) {
  __builtin_amdgcn_global_load_lds((__attribute__((address_space(1))) const void*)g,
                                   (__attribute__((address_space(3))) void*)l, 16, 0, 0);
}

// ---------------- fused K/V GEMM: [kq|v] = A[M,1024] @ Wkv[2048,1024]^T ----------------
__global__ __launch_bounds__(256, 2)
void gemm_kv(const bf16* __restrict__ A, const bf16* __restrict__ B,
             bf16* __restrict__ kout, bf16* __restrict__ vout)
{
  __shared__ __align__(16) bf16 As[128 * 64];
  __shared__ __align__(16) bf16 Bs[128 * 64];
  const int tid  = threadIdx.x;
  const int wave = tid >> 6, lane = tid & 63;
  const int wm = wave >> 1, wn = wave & 1;
  const int id  = blockIdx.y * 16 + blockIdx.x;
  const int vid = (id & 7) * 1024 + (id >> 3);     // XCD-chunked bijective swizzle
  const int brow = (vid >> 4) * 128, bcol = (vid & 15) * 128;
  const int r8 = lane >> 3, c8 = (lane & 7) * 8;
  const int cl = lane & 15, rh = lane >> 4;
  const int K = 1024;

  f32x4 acc[4][4] = {};

  for (int k0 = 0; k0 < K; k0 += 64) {
    __syncthreads();
#pragma unroll
    for (int i = 0; i < 4; ++i)
      gload16(A + (size_t)(brow + i * 32 + wave * 8 + r8) * K + k0 + c8, &As[(i * 32 + wave * 8) * 64]);
#pragma unroll
    for (int i = 0; i < 4; ++i)
      gload16(B + (size_t)(bcol + i * 32 + wave * 8 + r8) * K + k0 + c8, &Bs[(i * 32 + wave * 8) * 64]);
    __syncthreads();
#pragma unroll
    for (int kk = 0; kk < 2; ++kk) {
      bf16x8 af[4], bfv[4];
#pragma unroll
      for (int m = 0; m < 4; ++m)
        af[m] = *(const bf16x8*)&As[(wm * 64 + m * 16 + cl) * 64 + kk * 32 + rh * 8];
#pragma unroll
      for (int n = 0; n < 4; ++n)
        bfv[n] = *(const bf16x8*)&Bs[(wn * 64 + n * 16 + cl) * 64 + kk * 32 + rh * 8];
#pragma unroll
      for (int m = 0; m < 4; ++m)
#pragma unroll
        for (int n = 0; n < 4; ++n)
          acc[m][n] = MFMA16(af[m], bfv[n], acc[m][n]);
    }
  }
  bf16* __restrict__ C = (bcol < 1024) ? kout : vout;
  const int cbase = (bcol < 1024) ? bcol : bcol - 1024;
#pragma unroll
  for (int m = 0; m < 4; ++m)
#pragma unroll
    for (int n = 0; n < 4; ++n) {
      int row0 = brow + wm * 64 + m * 16 + rh * 4;
      int col  = cbase + wn * 64 + n * 16 + cl;
#pragma unroll
      for (int r = 0; r < 4; ++r)
        C[(size_t)(row0 + r) * 1024 + col] = (bf16)acc[m][n][r];
    }
}

// ---------------- generic 64x64 GEMM (z selects problem): C[M,N] = A[M,K] @ B[N,K]^T ----------------
template<int OUT_F32>
__global__ __launch_bounds__(256, 4)
void gemm_bt64(const bf16* __restrict__ A0, const bf16* __restrict__ B0, void* __restrict__ C0,
               const bf16* __restrict__ A1, const bf16* __restrict__ B1, void* __restrict__ C1,
               int N, int K)
{
  const bf16* A = blockIdx.z ? A1 : A0;
  const bf16* B = blockIdx.z ? B1 : B0;
  void* C = blockIdx.z ? C1 : C0;
  __shared__ __align__(16) bf16 As[64 * 64];
  __shared__ __align__(16) bf16 Bs[64 * 64];
  const int tid = threadIdx.x, wave = tid >> 6, lane = tid & 63;
  const int wm = wave >> 1, wn = wave & 1;
  const int brow = blockIdx.y * 64, bcol = blockIdx.x * 64;
  const int r8 = lane >> 3, c8 = (lane & 7) * 8;
  const int cl = lane & 15, rh = lane >> 4;
  f32x4 acc[2][2] = {};

  for (int k0 = 0; k0 < K; k0 += 64) {
    __syncthreads();
    gload16(A + (size_t)(brow + wave * 16 + r8) * K + k0 + c8,     &As[(wave * 16) * 64]);
    gload16(A + (size_t)(brow + wave * 16 + 8 + r8) * K + k0 + c8, &As[(wave * 16 + 8) * 64]);
    gload16(B + (size_t)(bcol + wave * 16 + r8) * K + k0 + c8,     &Bs[(wave * 16) * 64]);
    gload16(B + (size_t)(bcol + wave * 16 + 8 + r8) * K + k0 + c8, &Bs[(wave * 16 + 8) * 64]);
    __syncthreads();
#pragma unroll
    for (int kk = 0; kk < 2; ++kk) {
      bf16x8 af[2], bfv[2];
#pragma unroll
      for (int m = 0; m < 2; ++m)
        af[m] = *(const bf16x8*)&As[(wm * 32 + m * 16 + cl) * 64 + kk * 32 + rh * 8];
#pragma unroll
      for (int n = 0; n < 2; ++n)
        bfv[n] = *(const bf16x8*)&Bs[(wn * 32 + n * 16 + cl) * 64 + kk * 32 + rh * 8];
#pragma unroll
      for (int m = 0; m < 2; ++m)
#pragma unroll
        for (int n = 0; n < 2; ++n)
          acc[m][n] = MFMA16(af[m], bfv[n], acc[m][n]);
    }
  }
#pragma unroll
  for (int m = 0; m < 2; ++m)
#pragma unroll
    for (int n = 0; n < 2; ++n) {
      int row0 = brow + wm * 32 + m * 16 + rh * 4;
      int col  = bcol + wn * 32 + n * 16 + cl;
#pragma unroll
      for (int r = 0; r < 4; ++r) {
        if (OUT_F32) ((float*)C)[(size_t)(row0 + r) * N + col] = acc[m][n][r];
        else         ((bf16*)C)[(size_t)(row0 + r) * N + col] = (bf16)acc[m][n][r];
      }
    }
}

// ---------------- SwiGLU-fused GEMM ----------------
__global__ __launch_bounds__(256, 4)
void gemm_swiglu(const bf16* __restrict__ A, const bf16* __restrict__ B12, bf16* __restrict__ G)
{
  __shared__ __align__(16) bf16 As[64 * 64];
  __shared__ __align__(16) bf16 B1s[64 * 64];
  __shared__ __align__(16) bf16 B2s[64 * 64];
  const int tid = threadIdx.x, wave = tid >> 6, lane = tid & 63;
  const int wm = wave >> 1, wn = wave & 1;
  const int brow = blockIdx.y * 64, bcol = blockIdx.x * 64;
  const int r8 = lane >> 3, c8 = (lane & 7) * 8;
  const int cl = lane & 15, rh = lane >> 4;
  f32x4 acc1[2][2] = {}, acc2[2][2] = {};

  for (int k0 = 0; k0 < 1024; k0 += 64) {
    __syncthreads();
    gload16(A   + (size_t)(brow + wave * 16 + r8) * 1024 + k0 + c8,            &As[(wave * 16) * 64]);
    gload16(A   + (size_t)(brow + wave * 16 + 8 + r8) * 1024 + k0 + c8,        &As[(wave * 16 + 8) * 64]);
    gload16(B12 + (size_t)(bcol + wave * 16 + r8) * 1024 + k0 + c8,            &B1s[(wave * 16) * 64]);
    gload16(B12 + (size_t)(bcol + wave * 16 + 8 + r8) * 1024 + k0 + c8,        &B1s[(wave * 16 + 8) * 64]);
    gload16(B12 + (size_t)(2048 + bcol + wave * 16 + r8) * 1024 + k0 + c8,     &B2s[(wave * 16) * 64]);
    gload16(B12 + (size_t)(2048 + bcol + wave * 16 + 8 + r8) * 1024 + k0 + c8, &B2s[(wave * 16 + 8) * 64]);
    __syncthreads();
#pragma unroll
    for (int kk = 0; kk < 2; ++kk) {
      bf16x8 af[2], b1v[2], b2v[2];
#pragma unroll
      for (int m = 0; m < 2; ++m)
        af[m] = *(const bf16x8*)&As[(wm * 32 + m * 16 + cl) * 64 + kk * 32 + rh * 8];
#pragma unroll
      for (int n = 0; n < 2; ++n) {
        b1v[n] = *(const bf16x8*)&B1s[(wn * 32 + n * 16 + cl) * 64 + kk * 32 + rh * 8];
        b2v[n] = *(const bf16x8*)&B2s[(wn * 32 + n * 16 + cl) * 64 + kk * 32 + rh * 8];
      }
#pragma unroll
      for (int m = 0; m < 2; ++m)
#pragma unroll
        for (int n = 0; n < 2; ++n) {
          acc1[m][n] = MFMA16(af[m], b1v[n], acc1[m][n]);
          acc2[m][n] = MFMA16(af[m], b2v[n], acc2[m][n]);
        }
    }
  }
#pragma unroll
  for (int m = 0; m < 2; ++m)
#pragma unroll
    for (int n = 0; n < 2; ++n) {
      int row0 = brow + wm * 32 + m * 16 + rh * 4;
      int col  = bcol + wn * 32 + n * 16 + cl;
#pragma unroll
      for (int r = 0; r < 4; ++r) {
        float h1 = acc1[m][n][r], h2 = acc2[m][n][r];
        G[(size_t)(row0 + r) * 2048 + col] = (bf16)(h1 / (1.f + __expf(-h1)) * h2);
      }
    }
}

// ---------------- fused attention: dots (MFMA) + slot-softmax + PV (VALU) ----------------
// grid (16 l-chunks, 32 b). Block: 4 waves; l-chunk = 128 columns.
__global__ __launch_bounds__(256, 2)
void fused_attn(const bf16* __restrict__ s, const bf16* __restrict__ kq,
                const bf16* __restrict__ v, float* __restrict__ part,
                float* __restrict__ attn_sum)
{
  const int lc = blockIdx.x, b = blockIdx.y;
  const int tid = threadIdx.x, wave = tid >> 6, lane = tid & 63;
  const int cl = lane & 15, rh = lane >> 4;
  __shared__ __align__(16) bf16 ss[16 * 1024];      // 32KB s_norm
  __shared__ __align__(16) bf16 ks[128 * 64];       // 16KB kq chunk
  __shared__ __align__(16) float p_lds[128 * 20];   // 10KB attn (padded)

  const bf16* sb = s + (size_t)b * 16 * 1024;
#pragma unroll
  for (int i = 0; i < 8; ++i)
    gload16(sb + i * 2048 + tid * 8, &ss[i * 2048 + wave * 512]);

  const bf16* kb = kq + ((size_t)b * 2048 + lc * 128) * 1024;
  f32x4 acc[2] = {};
  for (int kt = 0; kt < 16; ++kt) {
    __syncthreads();
#pragma unroll
    for (int i = 0; i < 4; ++i) {
      int row = i * 32 + wave * 8 + (lane >> 3);
      gload16(kb + (size_t)row * 1024 + kt * 64 + (lane & 7) * 8, &ks[(i * 32 + wave * 8) * 64]);
    }
    __syncthreads();
#pragma unroll
    for (int kk = 0; kk < 2; ++kk) {
      bf16x8 af = *(const bf16x8*)&ss[cl * 1024 + kt * 64 + kk * 32 + rh * 8];
#pragma unroll
      for (int n = 0; n < 2; ++n) {
        bf16x8 bfv = *(const bf16x8*)&ks[(wave * 32 + n * 16 + cl) * 64 + kk * 32 + rh * 8];
        acc[n] = MFMA16(af, bfv, acc[n]);
      }
    }
  }
  // softmax over 16 slots per l; lane holds slots rh*4+r at l = wave*32 + n*16 + cl
  const float scale = 0.03125f;
  float rs[4] = {0.f, 0.f, 0.f, 0.f};
#pragma unroll
  for (int n = 0; n < 2; ++n) {
    float x[4];
#pragma unroll
    for (int r = 0; r < 4; ++r) x[r] = acc[n][r] * scale;
    float mx = fmaxf(fmaxf(x[0], x[1]), fmaxf(x[2], x[3]));
    mx = fmaxf(mx, __shfl_xor(mx, 16));
    mx = fmaxf(mx, __shfl_xor(mx, 32));
    float e[4], sm = 0.f;
#pragma unroll
    for (int r = 0; r < 4; ++r) { e[r] = __expf(x[r] - mx); sm += e[r]; }
    sm += __shfl_xor(sm, 16);
    sm += __shfl_xor(sm, 32);
    float inv = 1.f / sm;
    f32x4 pk;
#pragma unroll
    for (int r = 0; r < 4; ++r) { float av = e[r] * inv; rs[r] += av; pk[r] = av; }
    int ll = wave * 32 + n * 16 + cl;
    *(f32x4*)&p_lds[ll * 20 + rh * 4] = pk;
  }
#pragma unroll
  for (int off = 1; off < 16; off <<= 1) {
#pragma unroll
    for (int r = 0; r < 4; ++r) rs[r] += __shfl_xor(rs[r], off);
  }
  if (cl == 0) {
#pragma unroll
    for (int r = 0; r < 4; ++r) atomicAdd(&attn_sum[b * 16 + rh * 4 + r], rs[r]);
  }
  __syncthreads();

  // PV: thread owns 4 d-columns; stream V chunk, P broadcast from LDS.
  const bf16* vb = v + ((size_t)b * 2048 + lc * 128) * 1024 + tid * 4;
  float pacc[16][4] = {};
  for (int l = 0; l < 128; ++l) {
    bf16x4 vv = *(const bf16x4*)(vb + (size_t)l * 1024);
    float vf0 = (float)vv[0], vf1 = (float)vv[1], vf2 = (float)vv[2], vf3 = (float)vv[3];
    float pv[16];
    *(f32x4*)&pv[0]  = *(const f32x4*)&p_lds[l * 20];
    *(f32x4*)&pv[4]  = *(const f32x4*)&p_lds[l * 20 + 4];
    *(f32x4*)&pv[8]  = *(const f32x4*)&p_lds[l * 20 + 8];
    *(f32x4*)&pv[12] = *(const f32x4*)&p_lds[l * 20 + 12];
#pragma unroll
    for (int n = 0; n < 16; ++n) {
      pacc[n][0] += pv[n] * vf0; pacc[n][1] += pv[n] * vf1;
      pacc[n][2] += pv[n] * vf2; pacc[n][3] += pv[n] * vf3;
    }
  }
  float* pb = part + ((size_t)(lc * 32 + b) * 16) * 1024 + tid * 4;
#pragma unroll
  for (int n = 0; n < 16; ++n)
    *(f32x4*)(pb + (size_t)n * 1024) = *(f32x4*)&pacc[n][0];
}

__global__ void updates_finalize(const float* __restrict__ part, const float* __restrict__ attn_sum,
                                 bf16* __restrict__ upd)
{
  int idx = blockIdx.x * 256 + threadIdx.x;     // over 512*1024
  int m = idx >> 10;
  float sm = 0.f;
#pragma unroll
  for (int ls = 0; ls < 16; ++ls) sm += part[idx + (size_t)ls * 524288];
  upd[idx] = (bf16)(sm / (attn_sum[m] + 1e-8f));
}

// ---------------- GRU pointwise + fused rmsnorm of new slots ----------------
__global__ __launch_bounds__(256)
void gru_pw_fused(const float* __restrict__ gi, const float* __restrict__ gh,
                  const float* __restrict__ bih, const float* __restrict__ bhh,
                  const float* __restrict__ g_sl,
                  float* __restrict__ slots, bf16* __restrict__ slots_bf,
                  bf16* __restrict__ s_bf, float* __restrict__ outp)
{
  const int m = blockIdx.x, tid = threadIdx.x;
  const int d0 = tid * 4;
  const size_t base = (size_t)m * 3072 + d0;
  f32x4 gir = *(const f32x4*)(gi + base),        ghr = *(const f32x4*)(gh + base);
  f32x4 giz = *(const f32x4*)(gi + base + 1024), ghz = *(const f32x4*)(gh + base + 1024);
  f32x4 gin = *(const f32x4*)(gi + base + 2048), ghn = *(const f32x4*)(gh + base + 2048);
  f32x4 br  = *(const f32x4*)(bih + d0),        bhr = *(const f32x4*)(bhh + d0);
  f32x4 bz  = *(const f32x4*)(bih + 1024 + d0), bhz = *(const f32x4*)(bhh + 1024 + d0);
  f32x4 bn  = *(const f32x4*)(bih + 2048 + d0), bhn = *(const f32x4*)(bhh + 2048 + d0);
  f32x4 h   = *(const f32x4*)(slots + (size_t)m * 1024 + d0);
  float o[4]; float ssum = 0.f;
#pragma unroll
  for (int j = 0; j < 4; ++j) {
    float r  = gir[j] + br[j] + ghr[j] + bhr[j];
    float z  = giz[j] + bz[j] + ghz[j] + bhz[j];
    float nn = gin[j] + bn[j];
    float hn = ghn[j] + bhn[j];
    r = 1.f / (1.f + expf(-r));
    z = 1.f / (1.f + expf(-z));
    nn = tanhf(nn + r * hn);
    o[j] = (1.f - z) * nn + z * h[j];
    ssum += o[j] * o[j];
  }
#pragma unroll
  for (int off = 32; off; off >>= 1) ssum += __shfl_xor(ssum, off);
  __shared__ float red[4];
  if ((tid & 63) == 0) red[tid >> 6] = ssum;
  __syncthreads();
  float tot = red[0] + red[1] + red[2] + red[3];
  float rsc = rsqrtf(tot * (1.f / 1024.f) + 1e-6f);
  f32x4 gv = *(const f32x4*)(g_sl + d0);
  f32x4 of; bf16x4 ob, sb;
#pragma unroll
  for (int j = 0; j < 4; ++j) { of[j] = o[j]; ob[j] = (bf16)o[j]; sb[j] = (bf16)(o[j] * rsc * gv[j]); }
  *(f32x4*)(slots + (size_t)m * 1024 + d0) = of;
  *(f32x4*)(outp  + (size_t)m * 1024 + d0) = of;
  *(bf16x4*)(slots_bf + (size_t)m * 1024 + d0) = ob;
  *(bf16x4*)(s_bf     + (size_t)m * 1024 + d0) = sb;
}

__global__ __launch_bounds__(256)
void init_slots_fused(const float* __restrict__ noise, const float* __restrict__ mu,
                      const float* __restrict__ sigma, const float* __restrict__ g_sl,
                      float* __restrict__ slots, bf16* __restrict__ slots_bf,
                      bf16* __restrict__ s_bf)
{
  const int m = blockIdx.x, tid = threadIdx.x;
  const int d0 = tid * 4;
  f32x4 nz = *(const f32x4*)(noise + (size_t)m * 1024 + d0);
  f32x4 mv = *(const f32x4*)(mu + d0);
  f32x4 sg = *(const f32x4*)(sigma + d0);
  float o[4]; float ssum = 0.f;
#pragma unroll
  for (int j = 0; j < 4; ++j) { o[j] = mv[j] + sg[j] * nz[j]; ssum += o[j] * o[j]; }
#pragma unroll
  for (int off = 32; off; off >>= 1) ssum += __shfl_xor(ssum, off);
  __shared__ float red[4];
  if ((tid & 63) == 0) red[tid >> 6] = ssum;
  __syncthreads();
  float tot = red[0] + red[1] + red[2] + red[3];
  float rsc = rsqrtf(tot * (1.f / 1024.f) + 1e-6f);
  f32x4 gv = *(const f32x4*)(g_sl + d0);
  f32x4 of; bf16x4 ob, sb;
#pragma unroll
  for (int j = 0; j < 4; ++j) { of[j] = o[j]; ob[j] = (bf16)o[j]; sb[j] = (bf16)(o[j] * rsc * gv[j]); }
  *(f32x4*)(slots + (size_t)m * 1024 + d0) = of;
  *(bf16x4*)(slots_bf + (size_t)m * 1024 + d0) = ob;
  *(bf16x4*)(s_bf     + (size_t)m * 1024 + d0) = sb;
}

__global__ __launch_bounds__(256)
void rmsnorm_cast(const float* __restrict__ x, const float* __restrict__ g, bf16* __restrict__ y)
{
  const int row = blockIdx.x, tid = threadIdx.x;
  float4 xv = ((const float4*)(x + (size_t)row * 1024))[tid];
  float ss = xv.x * xv.x + xv.y * xv.y + xv.z * xv.z + xv.w * xv.w;
#pragma unroll
  for (int off = 32; off; off >>= 1) ss += __shfl_xor(ss, off);
  __shared__ float red[4];
  if ((tid & 63) == 0) red[tid >> 6] = ss;
  __syncthreads();
  float tot = red[0] + red[1] + red[2] + red[3];
  float rs = rsqrtf(tot * (1.f / 1024.f) + 1e-6f);
  float4 gv = ((const float4*)g)[tid];
  bf16x4 o;
  o[0] = (bf16)(xv.x * rs * gv.x); o[1] = (bf16)(xv.y * rs * gv.y);
  o[2] = (bf16)(xv.z * rs * gv.z); o[3] = (bf16)(xv.w * rs * gv.w);
  *(bf16x4*)(y + (size_t)row * 1024 + tid * 4) = o;
}

// ---------------- transpose f32 -> bf16 (1024x1024) ----------------
__global__ __launch_bounds__(256)
void transpose_cast(const float* __restrict__ in, bf16* __restrict__ out)
{
  __shared__ float tile[32][33];
  const int bx = blockIdx.x * 32, by = blockIdx.y * 32;
  const int tx = threadIdx.x & 31, ty = threadIdx.x >> 5;   // ty 0..7
#pragma unroll
  for (int i = 0; i < 32; i += 8)
    tile[ty + i][tx] = in[(size_t)(by + ty + i) * 1024 + bx + tx];
  __syncthreads();
#pragma unroll
  for (int i = 0; i < 32; i += 8)
    out[(size_t)(bx + ty + i) * 1024 + by + tx] = (bf16)tile[tx][ty + i];
}

__global__ void cast_bf16_x4(const float* __restrict__ x, bf16* __restrict__ y)
{
  int i = (blockIdx.x * 256 + threadIdx.x) * 4;
  float4 v = *(const float4*)(x + i);
  bf16x4 o; o[0] = (bf16)v.x; o[1] = (bf16)v.y; o[2] = (bf16)v.z; o[3] = (bf16)v.w;
  *(bf16x4*)(y + i) = o;
}

// ---------------- host ----------------
extern "C" void kernel_launch(void* const* d_in, const int* in_sizes, int n_in,
                              void* d_out, int out_size, void* d_ws, size_t ws_size,
                              hipStream_t stream)
{
  const float* enc    = (const float*)d_in[0];
  const float* noise  = (const float*)d_in[1];
  const float* mu     = (const float*)d_in[2];
  const float* sigma  = (const float*)d_in[3];
  const float* g_in   = (const float*)d_in[4];
  const float* g_sl   = (const float*)d_in[5];
  const float* Wq     = (const float*)d_in[6];
  const float* Wk     = (const float*)d_in[7];
  const float* Wv     = (const float*)d_in[8];
  const float* w1     = (const float*)d_in[9];
  const float* w2     = (const float*)d_in[10];
  const float* w3     = (const float*)d_in[11];
  const float* Wih    = (const float*)d_in[12];
  const float* Whh    = (const float*)d_in[13];
  const float* bih    = (const float*)d_in[14];
  const float* bhh    = (const float*)d_in[15];

  char* p = (char*)d_ws;
  auto alloc = [&](size_t bytes) { char* r = p; p += (bytes + 255) & ~(size_t)255; return (void*)r; };

  bf16* inputs  = (bf16*)alloc((size_t)32 * 2048 * 1024 * 2);  // 128MB
  bf16* kqbuf   = (bf16*)alloc((size_t)32 * 2048 * 1024 * 2);  // 128MB
  bf16* vbuf    = (bf16*)alloc((size_t)32 * 2048 * 1024 * 2);  // 128MB
  bf16* wkv_b   = (bf16*)alloc((size_t)2048 * 1024 * 2);       // [M; Wv]
  bf16* wqT_b   = (bf16*)alloc((size_t)1024 * 1024 * 2);
  bf16* wkT_b   = (bf16*)alloc((size_t)1024 * 1024 * 2);
  bf16* w12_b   = (bf16*)alloc((size_t)4096 * 1024 * 2);       // [w1; w2]
  bf16* w3_b    = (bf16*)alloc((size_t)1024 * 2048 * 2);
  bf16* wih_b   = (bf16*)alloc((size_t)3072 * 1024 * 2);
  bf16* whh_b   = (bf16*)alloc((size_t)3072 * 1024 * 2);
  float* slots  = (float*)alloc(512 * 1024 * 4);
  bf16* slots_bf= (bf16*)alloc(512 * 1024 * 2);
  bf16* s_bf    = (bf16*)alloc(512 * 1024 * 2);
  float* attn_sum = (float*)alloc(32 * 16 * 4);
  float* part   = (float*)alloc((size_t)16 * 512 * 1024 * 4);  // 32MB
  bf16* upd_bf  = (bf16*)alloc(512 * 1024 * 2);
  bf16* g_bf    = (bf16*)alloc((size_t)512 * 2048 * 2);
  bf16* swout   = (bf16*)alloc(512 * 1024 * 2);
  float* gif    = (float*)alloc((size_t)512 * 3072 * 4);
  float* ghf    = (float*)alloc((size_t)512 * 3072 * 4);

  // ---- precompute: M = Wq^T @ Wk  (folds q-projection into K-projection) ----
  transpose_cast<<<dim3(32, 32), 256, 0, stream>>>(Wq, wqT_b);
  transpose_cast<<<dim3(32, 32), 256, 0, stream>>>(Wk, wkT_b);
  // M[d,e] = sum_t WqT[d,t] * WkT[e,t]  -> into wkv_b rows 0..1023
  gemm_bt64<0><<<dim3(16, 16, 1), 256, 0, stream>>>(wqT_b, wkT_b, wkv_b, wqT_b, wkT_b, wkv_b, 1024, 1024);
  cast_bf16_x4<<<1024, 256, 0, stream>>>(Wv, wkv_b + (size_t)1024 * 1024);
  cast_bf16_x4<<<2048, 256, 0, stream>>>(w1, w12_b);
  cast_bf16_x4<<<2048, 256, 0, stream>>>(w2, w12_b + (size_t)2048 * 1024);
  cast_bf16_x4<<<2048, 256, 0, stream>>>(w3, w3_b);
  cast_bf16_x4<<<3072, 256, 0, stream>>>(Wih, wih_b);
  cast_bf16_x4<<<3072, 256, 0, stream>>>(Whh, whh_b);

  // ---- stage 1 ----
  rmsnorm_cast<<<65536, 256, 0, stream>>>(enc, g_in, inputs);
  init_slots_fused<<<512, 256, 0, stream>>>(noise, mu, sigma, g_sl, slots, slots_bf, s_bf);
  gemm_kv<<<dim3(16, 512), 256, 0, stream>>>(inputs, wkv_b, kqbuf, vbuf);

  // ---- iterations ----
  for (int it = 0; it < 4; ++it) {
    hipMemsetAsync(attn_sum, 0, 32 * 16 * 4, stream);
    fused_attn<<<dim3(16, 32), 256, 0, stream>>>(s_bf, kqbuf, vbuf, part, attn_sum);
    updates_finalize<<<2048, 256, 0, stream>>>(part, attn_sum, upd_bf);
    gemm_swiglu<<<dim3(32, 8), 256, 0, stream>>>(upd_bf, w12_b, g_bf);
    gemm_bt64<0><<<dim3(16, 8, 1), 256, 0, stream>>>(g_bf, w3_b, swout, g_bf, w3_b, swout, 1024, 2048);
    gemm_bt64<1><<<dim3(48, 8, 2), 256, 0, stream>>>(swout, wih_b, gif, slots_bf, whh_b, ghf, 3072, 1024);
    float* outp = (it == 3) ? (float*)d_out : slots;
    gru_pw_fused<<<512, 256, 0, stream>>>(gif, ghf, bih, bhh, g_sl, slots, slots_bf, s_bf, outp);
  }
}